// Round 1
// baseline (619.007 us; speedup 1.0000x reference)
//
#include <hip/hip_runtime.h>
#include <math.h>

#define NUM_C 16
#define DIMS 512
#define ROWS_PB 256   // rows per block in segsum

// ---------------- Kernel 1: class counts histogram ----------------
__global__ __launch_bounds__(256) void k_counts(const int* __restrict__ bids,
                                                int* __restrict__ counts, int n) {
    __shared__ int hist[NUM_C];
    int tid = threadIdx.x;
    if (tid < NUM_C) hist[tid] = 0;
    __syncthreads();
    int idx = blockIdx.x * 256 + tid;
    int stride = gridDim.x * 256;
    for (int i = idx; i < n; i += stride) atomicAdd(&hist[bids[i]], 1);
    __syncthreads();
    if (tid < NUM_C) atomicAdd(&counts[tid], hist[tid]);
}

// ---------------- Kernel 2: per-class sum and sum-of-squares ----------------
// Grid: (N/ROWS_PB) * 2 blocks. blockIdx & 1 = column group (256 dims each),
// blockIdx >> 1 = row chunk. 256 threads = 4 waves; each wave handles 2 rows
// per iteration with float4 loads (16 B/lane, fully coalesced).
// LDS accumulators are swizzled: value for local dim (lane*4+k) is stored at
// [c*256 + k*64 + lane] so the 64 lanes of a wave hit stride-1 addresses
// (2 lanes/bank -> conflict-free per m136).
__global__ __launch_bounds__(256) void k_segsum(const float* __restrict__ hidden,
                                                const int* __restrict__ bids,
                                                float* __restrict__ gsum,
                                                float* __restrict__ gsq) {
    __shared__ float lsum[NUM_C * 256];
    __shared__ float lsq[NUM_C * 256];
    const int tid = threadIdx.x;
    const int g = blockIdx.x & 1;
    const int chunk = blockIdx.x >> 1;
    for (int i = tid; i < NUM_C * 256; i += 256) { lsum[i] = 0.f; lsq[i] = 0.f; }
    __syncthreads();

    const int lane = tid & 63, wid = tid >> 6;
    const int rowbase = chunk * ROWS_PB;
    const int dimbase = g * 256;

    for (int it = 0; it < ROWS_PB / 8; ++it) {
        const int row0 = rowbase + it * 8 + wid * 2;
        const int row1 = row0 + 1;
        const int c0 = bids[row0];
        const int c1 = bids[row1];
        const float4 h0 = *reinterpret_cast<const float4*>(
            hidden + (size_t)row0 * DIMS + dimbase + lane * 4);
        const float4 h1 = *reinterpret_cast<const float4*>(
            hidden + (size_t)row1 * DIMS + dimbase + lane * 4);
        float* ps0 = &lsum[c0 * 256]; float* pq0 = &lsq[c0 * 256];
        atomicAdd(ps0 + lane,       h0.x); atomicAdd(pq0 + lane,       h0.x * h0.x);
        atomicAdd(ps0 + 64 + lane,  h0.y); atomicAdd(pq0 + 64 + lane,  h0.y * h0.y);
        atomicAdd(ps0 + 128 + lane, h0.z); atomicAdd(pq0 + 128 + lane, h0.z * h0.z);
        atomicAdd(ps0 + 192 + lane, h0.w); atomicAdd(pq0 + 192 + lane, h0.w * h0.w);
        float* ps1 = &lsum[c1 * 256]; float* pq1 = &lsq[c1 * 256];
        atomicAdd(ps1 + lane,       h1.x); atomicAdd(pq1 + lane,       h1.x * h1.x);
        atomicAdd(ps1 + 64 + lane,  h1.y); atomicAdd(pq1 + 64 + lane,  h1.y * h1.y);
        atomicAdd(ps1 + 128 + lane, h1.z); atomicAdd(pq1 + 128 + lane, h1.z * h1.z);
        atomicAdd(ps1 + 192 + lane, h1.w); atomicAdd(pq1 + 192 + lane, h1.w * h1.w);
    }
    __syncthreads();

    // flush to global (de-swizzle: storage (k,l) <-> local dim l*4+k)
    for (int s = tid; s < NUM_C * 256; s += 256) {
        const int c = s >> 8;
        const int loc = s & 255;
        const int k = loc >> 6, l = loc & 63;
        const int gdim = dimbase + l * 4 + k;
        atomicAdd(&gsum[c * DIMS + gdim], lsum[s]);
        atomicAdd(&gsq[c * DIMS + gdim], lsq[s]);
    }
}

// ---------------- Kernel 3: finalize means / withins ----------------
__global__ __launch_bounds__(256) void k_final(const float* __restrict__ gsum,
                                               const float* __restrict__ gsq,
                                               const int* __restrict__ counts,
                                               float* __restrict__ means,
                                               float* __restrict__ withins) {
    int idx = blockIdx.x * 256 + threadIdx.x;
    if (idx >= NUM_C * DIMS) return;
    int c = idx / DIMS;
    float n = (float)counts[c];
    float s = gsum[idx];
    float m = s / n;
    means[idx] = m;
    float w = gsq[idx] - s * s / n;   // == seg((h-m)^2)
    withins[idx] = w > 0.f ? w : 0.f;
}

// ---------------- betainc (regularized incomplete beta), double ----------------
__device__ double betacf_d(double a, double b, double x) {
    const double FPMIN = 1e-300, EPS = 1e-15;
    double qab = a + b, qap = a + 1.0, qam = a - 1.0;
    double cc = 1.0, dd = 1.0 - qab * x / qap;
    if (fabs(dd) < FPMIN) dd = FPMIN;
    dd = 1.0 / dd;
    double h = dd;
    for (int m = 1; m <= 2000; ++m) {
        double m2 = 2.0 * m;
        double aa = m * (b - m) * x / ((qam + m2) * (a + m2));
        dd = 1.0 + aa * dd; if (fabs(dd) < FPMIN) dd = FPMIN;
        cc = 1.0 + aa / cc; if (fabs(cc) < FPMIN) cc = FPMIN;
        dd = 1.0 / dd;
        h *= dd * cc;
        aa = -(a + m) * (qab + m) * x / ((a + m2) * (qap + m2));
        dd = 1.0 + aa * dd; if (fabs(dd) < FPMIN) dd = FPMIN;
        cc = 1.0 + aa / cc; if (fabs(cc) < FPMIN) cc = FPMIN;
        dd = 1.0 / dd;
        double del = dd * cc;
        h *= del;
        if (fabs(del - 1.0) < EPS) break;
    }
    return h;
}

__device__ double betainc_reg(double a, double b, double x) {
    if (x <= 0.0) return 1e-300;
    if (x >= 1.0) return 1.0;
    double lnbt = lgamma(a + b) - lgamma(a) - lgamma(b) + a * log(x) + b * log1p(-x);
    double bt = exp(lnbt);
    double r;
    if (x < (a + 1.0) / (a + b + 2.0)) r = bt * betacf_d(a, b, x) / a;
    else                               r = 1.0 - bt * betacf_d(b, a, 1.0 - x) / b;
    if (r < 1e-300) r = 1e-300;
    if (r > 1.0) r = 1.0;
    return r;
}

// ---------------- Kernel 4: per-pair betainc + top-k log-sum ----------------
// One block (512 threads) per pair (i<j): thread t computes dim t's betainc,
// bitonic-sorts all 512 values descending in LDS, sums log of the top d,
// atomically accumulates -sum into out.
__global__ __launch_bounds__(512) void k_pairs(const float* __restrict__ means,
                                               const float* __restrict__ withins,
                                               const int* __restrict__ counts,
                                               const int* __restrict__ dptr,
                                               float* __restrict__ out) {
    __shared__ double vals[DIMS];
    __shared__ double wsum[8];
    const int tid = threadIdx.x;

    // decode pair index -> (i, j), i < j
    int p = blockIdx.x, i = 0, rem = p;
    while (rem >= NUM_C - 1 - i) { rem -= NUM_C - 1 - i; ++i; }
    const int j = i + 1 + rem;

    const double ni = (double)counts[i], nj = (double)counts[j];
    const double pc = ni + nj;
    double d2 = pc - 2.0;
    if (d2 == 0.0) d2 = 1e-5;
    const double b = d2 * 0.5;

    {
        const int k = tid;
        const double mi = (double)means[i * DIMS + k];
        const double mj = (double)means[j * DIMS + k];
        const double hd = (mi - mj) * 0.5;
        const double between = hd * hd * pc;
        const double within = (double)withins[i * DIMS + k] + (double)withins[j * DIMS + k];
        double x = between / (between + within);
        if (!(x >= 1e-37)) x = 1e-37;            // also catches NaN (0/0)
        if (x > 1.0 - 1e-5) x = 1.0 - 1e-5;
        vals[k] = betainc_reg(0.5, b, x);
    }

    // bitonic sort, descending
    for (int kk = 2; kk <= DIMS; kk <<= 1) {
        for (int jj = kk >> 1; jj > 0; jj >>= 1) {
            __syncthreads();
            const int ixj = tid ^ jj;
            if (ixj > tid) {
                const double va = vals[tid], vb = vals[ixj];
                const bool sw = ((tid & kk) == 0) ? (va < vb) : (va > vb);
                if (sw) { vals[tid] = vb; vals[ixj] = va; }
            }
        }
    }
    __syncthreads();

    const int d = *dptr;
    double part = (tid < d) ? log(vals[tid]) : 0.0;
    for (int off = 32; off > 0; off >>= 1) part += __shfl_down(part, off, 64);
    if ((tid & 63) == 0) wsum[tid >> 6] = part;
    __syncthreads();
    if (tid == 0) {
        double t = 0.0;
        for (int w = 0; w < 8; ++w) t += wsum[w];
        atomicAdd(out, (float)(-t));
    }
}

// ---------------- launch ----------------
extern "C" void kernel_launch(void* const* d_in, const int* in_sizes, int n_in,
                              void* d_out, int out_size, void* d_ws, size_t ws_size,
                              hipStream_t stream) {
    const float* hidden = (const float*)d_in[0];
    const int* bids = (const int*)d_in[1];
    const int* dptr = (const int*)d_in[2];
    float* out = (float*)d_out;
    const int N = in_sizes[1];

    // workspace layout (all well under any reasonable ws_size; ~128.25 KB)
    char* ws = (char*)d_ws;
    int* counts   = (int*)ws;                                  // 16 ints
    float* gsum   = (float*)(ws + 256);                        // 16*512 f32
    float* gsq    = (float*)(ws + 256 + 32768);                // 16*512 f32
    float* means  = (float*)(ws + 256 + 65536);                // 16*512 f32
    float* withins= (float*)(ws + 256 + 65536 + 32768);        // 16*512 f32

    hipMemsetAsync(d_ws, 0, 256 + 65536, stream);              // counts + gsum + gsq
    hipMemsetAsync(d_out, 0, sizeof(float), stream);

    k_counts<<<256, 256, 0, stream>>>(bids, counts, N);
    k_segsum<<<(N / ROWS_PB) * 2, 256, 0, stream>>>(hidden, bids, gsum, gsq);
    k_final<<<(NUM_C * DIMS + 255) / 256, 256, 0, stream>>>(gsum, gsq, counts, means, withins);
    k_pairs<<<NUM_C * (NUM_C - 1) / 2, 512, 0, stream>>>(means, withins, counts, dptr, out);
}

// Round 2
// 258.895 us; speedup vs baseline: 2.3910x; 2.3910x over previous
//
#include <hip/hip_runtime.h>
#include <math.h>

#define NUM_C 16
#define DIMS 512
#define SEG_ROWS 256      // rows per segsum block
#define NREP 8            // global accumulator replicas (contention spread)

__device__ inline void atomAddF(float* p, float v) { unsafeAtomicAdd(p, v); }

// ---------------- Kernel 1: class counts histogram (int atomics are native) ----
__global__ __launch_bounds__(256) void k_counts(const int* __restrict__ bids,
                                                int* __restrict__ counts, int n) {
    __shared__ int hist[NUM_C];
    int tid = threadIdx.x;
    if (tid < NUM_C) hist[tid] = 0;
    __syncthreads();
    for (int i = blockIdx.x * 256 + tid; i < n; i += gridDim.x * 256)
        atomicAdd(&hist[bids[i]], 1);
    __syncthreads();
    if (tid < NUM_C) atomicAdd(&counts[tid], hist[tid]);
}

// ---------------- Kernel 2: per-class sum / sum-of-squares ----------------
// Grid: 2 dim-halves x 256 row-chunks = 512 blocks x 256 threads.
// All threads of a block process the SAME row each iteration (class is
// uniform -> scalar load). Thread t exclusively owns LDS slots
// {sum,sq}[c][t] for all c -> plain read-add-write, NO atomics, no races.
// LDS float2 at stride 8 B: 2 lanes/bank = conflict-free (m136).
__global__ __launch_bounds__(256) void k_segsum(const float* __restrict__ hidden,
                                                const int* __restrict__ bids,
                                                float* __restrict__ gsum_rep,
                                                float* __restrict__ gsq_rep) {
    __shared__ float acc[NUM_C * 256 * 2];   // [(c*256+t)*2] = {sum, sq}; 32 KB
    const int tid = threadIdx.x;
    const int g = blockIdx.x & 1;            // dim half (0: dims 0-255, 1: 256-511)
    const int chunk = blockIdx.x >> 1;       // row chunk

    #pragma unroll
    for (int c = 0; c < NUM_C; ++c) {        // zero own column only (exclusive)
        acc[(c * 256 + tid) * 2]     = 0.f;
        acc[(c * 256 + tid) * 2 + 1] = 0.f;
    }
    // no sync needed: each thread touches only its own column until flush

    const int rowbase = chunk * SEG_ROWS;
    const float* hp = hidden + (size_t)rowbase * DIMS + g * 256 + tid;

    for (int it = 0; it < SEG_ROWS; it += 8) {
        int cs[8]; float vs[8];
        #pragma unroll
        for (int u = 0; u < 8; ++u) cs[u] = bids[rowbase + it + u];   // uniform -> s_load
        #pragma unroll
        for (int u = 0; u < 8; ++u) vs[u] = hp[(size_t)(it + u) * DIMS]; // 8 indep 256B wave-loads
        #pragma unroll
        for (int u = 0; u < 8; ++u) {
            float2* slot = reinterpret_cast<float2*>(&acc[(cs[u] * 256 + tid) * 2]);
            float2 s = *slot;
            s.x += vs[u];
            s.y += vs[u] * vs[u];
            *slot = s;
        }
    }
    __syncthreads();

    // flush: native f32 atomics into replica (blockIdx>>1)&7 to spread contention
    const int rep = (blockIdx.x >> 1) & (NREP - 1);
    for (int s = tid; s < NUM_C * 256; s += 256) {
        const int c = s >> 8, l = s & 255;
        const int gdim = g * 256 + l;
        atomAddF(&gsum_rep[(size_t)rep * NUM_C * DIMS + c * DIMS + gdim], acc[s * 2]);
        atomAddF(&gsq_rep [(size_t)rep * NUM_C * DIMS + c * DIMS + gdim], acc[s * 2 + 1]);
    }
}

// ---------------- Kernel 3: reduce replicas, finalize means / withins --------
__global__ __launch_bounds__(256) void k_final(const float* __restrict__ gsum_rep,
                                               const float* __restrict__ gsq_rep,
                                               const int* __restrict__ counts,
                                               float* __restrict__ means,
                                               float* __restrict__ withins) {
    int idx = blockIdx.x * 256 + threadIdx.x;
    if (idx >= NUM_C * DIMS) return;
    float s = 0.f, q = 0.f;
    #pragma unroll
    for (int r = 0; r < NREP; ++r) {
        s += gsum_rep[r * NUM_C * DIMS + idx];
        q += gsq_rep [r * NUM_C * DIMS + idx];
    }
    int c = idx / DIMS;
    float n = (float)counts[c];
    float m = s / n;
    means[idx] = m;
    float w = q - s * s / n;       // == seg((h-m)^2)
    withins[idx] = w > 0.f ? w : 0.f;
}

// ---------------- betainc (regularized incomplete beta), double --------------
__device__ double betacf_d(double a, double b, double x) {
    const double FPMIN = 1e-300, EPS = 1e-15;
    double qab = a + b, qap = a + 1.0, qam = a - 1.0;
    double cc = 1.0, dd = 1.0 - qab * x / qap;
    if (fabs(dd) < FPMIN) dd = FPMIN;
    dd = 1.0 / dd;
    double h = dd;
    for (int m = 1; m <= 1000; ++m) {
        double m2 = 2.0 * m;
        double aa = m * (b - m) * x / ((qam + m2) * (a + m2));
        dd = 1.0 + aa * dd; if (fabs(dd) < FPMIN) dd = FPMIN;
        cc = 1.0 + aa / cc; if (fabs(cc) < FPMIN) cc = FPMIN;
        dd = 1.0 / dd;
        h *= dd * cc;
        aa = -(a + m) * (qab + m) * x / ((a + m2) * (qap + m2));
        dd = 1.0 + aa * dd; if (fabs(dd) < FPMIN) dd = FPMIN;
        cc = 1.0 + aa / cc; if (fabs(cc) < FPMIN) cc = FPMIN;
        dd = 1.0 / dd;
        double del = dd * cc;
        h *= del;
        if (fabs(del - 1.0) < EPS) break;
    }
    return h;
}

__device__ double betainc_reg(double a, double b, double x) {
    if (x <= 0.0) return 1e-300;
    if (x >= 1.0) return 1.0;
    double lnbt = lgamma(a + b) - lgamma(a) - lgamma(b) + a * log(x) + b * log1p(-x);
    double bt = exp(lnbt);
    double r;
    if (x < (a + 1.0) / (a + b + 2.0)) r = bt * betacf_d(a, b, x) / a;
    else                               r = 1.0 - bt * betacf_d(b, a, 1.0 - x) / b;
    if (r < 1e-300) r = 1e-300;
    if (r > 1.0) r = 1.0;
    return r;
}

// ---------------- Kernel 4: per-pair x, sort, betainc on top-d only ----------
// betainc(0.5, b, x) is monotone increasing in x with (a,b) fixed per pair, so
// top-d of betainc == betainc of top-d x. Sort cheap f32 x, CF only d values.
__global__ __launch_bounds__(512) void k_pairs(const float* __restrict__ means,
                                               const float* __restrict__ withins,
                                               const int* __restrict__ counts,
                                               const int* __restrict__ dptr,
                                               float* __restrict__ out) {
    __shared__ float xs[DIMS];
    __shared__ double wsum[8];
    const int tid = threadIdx.x;

    int p = blockIdx.x, i = 0, rem = p;
    while (rem >= NUM_C - 1 - i) { rem -= NUM_C - 1 - i; ++i; }
    const int j = i + 1 + rem;

    const float ni = (float)counts[i], nj = (float)counts[j];
    const float pc = ni + nj;

    {
        float mi = means[i * DIMS + tid], mj = means[j * DIMS + tid];
        float hd = (mi - mj) * 0.5f;
        float between = hd * hd * pc;
        float within = withins[i * DIMS + tid] + withins[j * DIMS + tid];
        float x = between / (between + within);
        if (!(x >= 1e-37f)) x = 1e-37f;        // also catches NaN
        const float XM = 1.0f - 1e-5f;
        if (x > XM) x = XM;
        xs[tid] = x;
    }

    // bitonic sort, descending (f32)
    for (int kk = 2; kk <= DIMS; kk <<= 1) {
        for (int jj = kk >> 1; jj > 0; jj >>= 1) {
            __syncthreads();
            const int ixj = tid ^ jj;
            if (ixj > tid) {
                const float va = xs[tid], vb = xs[ixj];
                const bool sw = ((tid & kk) == 0) ? (va < vb) : (va > vb);
                if (sw) { xs[tid] = vb; xs[ixj] = va; }
            }
        }
    }
    __syncthreads();

    const int d = *dptr;
    double part = 0.0;
    if (tid < d) {
        double d2 = (double)pc - 2.0;
        if (d2 == 0.0) d2 = 1e-5;
        part = log(betainc_reg(0.5, d2 * 0.5, (double)xs[tid]));
    }
    for (int off = 32; off > 0; off >>= 1) part += __shfl_down(part, off, 64);
    if ((tid & 63) == 0) wsum[tid >> 6] = part;
    __syncthreads();
    if (tid == 0) {
        double t = 0.0;
        for (int w = 0; w < 8; ++w) t += wsum[w];
        atomAddF(out, (float)(-t));
    }
}

// ---------------- launch ----------------
extern "C" void kernel_launch(void* const* d_in, const int* in_sizes, int n_in,
                              void* d_out, int out_size, void* d_ws, size_t ws_size,
                              hipStream_t stream) {
    const float* hidden = (const float*)d_in[0];
    const int* bids = (const int*)d_in[1];
    const int* dptr = (const int*)d_in[2];
    float* out = (float*)d_out;
    const int N = in_sizes[1];

    // workspace layout (~590 KB)
    char* ws = (char*)d_ws;
    int* counts     = (int*)ws;                                   // 16 ints (pad 256)
    float* gsum_rep = (float*)(ws + 256);                         // NREP*16*512 f32
    float* gsq_rep  = (float*)(ws + 256 + NREP * NUM_C * DIMS * 4);
    float* means    = (float*)(ws + 256 + 2 * NREP * NUM_C * DIMS * 4);
    float* withins  = (float*)(ws + 256 + 2 * NREP * NUM_C * DIMS * 4 + NUM_C * DIMS * 4);

    hipMemsetAsync(d_ws, 0, 256 + 2 * NREP * NUM_C * DIMS * 4, stream);
    hipMemsetAsync(d_out, 0, sizeof(float), stream);

    k_counts<<<64, 256, 0, stream>>>(bids, counts, N);
    k_segsum<<<(N / SEG_ROWS) * 2, 256, 0, stream>>>(hidden, bids, gsum_rep, gsq_rep);
    k_final<<<(NUM_C * DIMS + 255) / 256, 256, 0, stream>>>(gsum_rep, gsq_rep, counts, means, withins);
    k_pairs<<<NUM_C * (NUM_C - 1) / 2, 512, 0, stream>>>(means, withins, counts, dptr, out);
}

// Round 6
// 237.889 us; speedup vs baseline: 2.6021x; 1.0883x over previous
//
#include <hip/hip_runtime.h>
#include <math.h>

#define NUM_C 16
#define DIMS 512
#define CHUNKS 32   // row-chunks per class in segsum -> 16*32 = 512 blocks

__device__ inline void atomAddF(float* p, float v) { unsafeAtomicAdd(p, v); }

// ---------------- K1: class counts ----------------
__global__ __launch_bounds__(256) void k_counts(const int* __restrict__ bids,
                                                int* __restrict__ counts, int n) {
    __shared__ int h[NUM_C];
    const int tid = threadIdx.x;
    if (tid < NUM_C) h[tid] = 0;
    __syncthreads();
    const int i0 = (blockIdx.x * 256 + tid) * 4;
    if (i0 + 3 < n) {
        int4 c4 = *reinterpret_cast<const int4*>(bids + i0);
        atomicAdd(&h[c4.x], 1); atomicAdd(&h[c4.y], 1);
        atomicAdd(&h[c4.z], 1); atomicAdd(&h[c4.w], 1);
    }
    __syncthreads();
    if (tid < NUM_C) atomicAdd(&counts[tid], h[tid]);
}

// ---------------- K2: exclusive prefix over 16 classes ----------------
__global__ void k_prefix(const int* __restrict__ counts,
                         int* __restrict__ offs, int* __restrict__ gcur) {
    if (threadIdx.x == 0) {
        int acc = 0;
        for (int c = 0; c < NUM_C; ++c) { offs[c] = acc; gcur[c] = acc; acc += counts[c]; }
    }
}

// ---------------- K3: scatter row indices grouped by class ----------------
__global__ __launch_bounds__(256) void k_scatter(const int* __restrict__ bids,
                                                 int* __restrict__ gcur,
                                                 int* __restrict__ perm, int n) {
    __shared__ int lh[NUM_C], lb[NUM_C], lc[NUM_C];
    const int tid = threadIdx.x;
    if (tid < NUM_C) lh[tid] = 0;
    __syncthreads();
    const int i0 = (blockIdx.x * 256 + tid) * 4;
    int4 c4 = make_int4(0, 0, 0, 0);
    const bool ok = (i0 + 3 < n);
    if (ok) {
        c4 = *reinterpret_cast<const int4*>(bids + i0);
        atomicAdd(&lh[c4.x], 1); atomicAdd(&lh[c4.y], 1);
        atomicAdd(&lh[c4.z], 1); atomicAdd(&lh[c4.w], 1);
    }
    __syncthreads();
    if (tid < NUM_C) { lb[tid] = atomicAdd(&gcur[tid], lh[tid]); lc[tid] = 0; }
    __syncthreads();
    if (ok) {
        perm[lb[c4.x] + atomicAdd(&lc[c4.x], 1)] = i0;
        perm[lb[c4.y] + atomicAdd(&lc[c4.y], 1)] = i0 + 1;
        perm[lb[c4.z] + atomicAdd(&lc[c4.z], 1)] = i0 + 2;
        perm[lb[c4.w] + atomicAdd(&lc[c4.w], 1)] = i0 + 3;
    }
}

// ---------------- K4: per-class sum / sumsq, register accumulators ----------
// Block = (class c, chunk). Class uniform per block -> acc in float4 regs.
// 256 threads: half = tid>>7 takes every 2nd row; 128 threads x float4 = full
// 2KB row, perfectly coalesced. No LDS in hot loop.
__global__ __launch_bounds__(256) void k_segsum(const float* __restrict__ hidden,
                                                const int* __restrict__ perm,
                                                const int* __restrict__ counts,
                                                const int* __restrict__ offs,
                                                float* __restrict__ gsum,
                                                float* __restrict__ gsq) {
    const int tid = threadIdx.x;
    const int c = blockIdx.x & (NUM_C - 1);
    const int chunk = blockIdx.x >> 4;
    const int cnt = counts[c];
    const int base = offs[c];
    const int len = (cnt + CHUNKS - 1) / CHUNKS;
    const int lo = chunk * len;
    const int hi = min(lo + len, cnt);
    const int half = tid >> 7, ht = tid & 127;

    float4 s = {0.f, 0.f, 0.f, 0.f}, q = {0.f, 0.f, 0.f, 0.f};
#define LOADROW(r) (*(reinterpret_cast<const float4*>(hidden + (size_t)(r) * DIMS) + ht))
#define ACC(v) { s.x += (v).x; s.y += (v).y; s.z += (v).z; s.w += (v).w; \
                 q.x += (v).x*(v).x; q.y += (v).y*(v).y; q.z += (v).z*(v).z; q.w += (v).w*(v).w; }
    int k = lo + half;
    for (; k + 6 < hi; k += 8) {
        const int r0 = perm[base + k],     r1 = perm[base + k + 2];
        const int r2 = perm[base + k + 4], r3 = perm[base + k + 6];
        const float4 v0 = LOADROW(r0), v1 = LOADROW(r1);
        const float4 v2 = LOADROW(r2), v3 = LOADROW(r3);
        ACC(v0); ACC(v1); ACC(v2); ACC(v3);
    }
    for (; k < hi; k += 2) {
        const int r0 = perm[base + k];
        const float4 v0 = LOADROW(r0);
        ACC(v0);
    }
#undef LOADROW
#undef ACC

    // combine the two halves through LDS, then native-f32 atomic flush
    __shared__ float red[128 * 8];
    if (half == 1) {
        float* p = &red[ht * 8];
        p[0] = s.x; p[1] = s.y; p[2] = s.z; p[3] = s.w;
        p[4] = q.x; p[5] = q.y; p[6] = q.z; p[7] = q.w;
    }
    __syncthreads();
    if (half == 0) {
        const float* p = &red[ht * 8];
        s.x += p[0]; s.y += p[1]; s.z += p[2]; s.w += p[3];
        q.x += p[4]; q.y += p[5]; q.z += p[6]; q.w += p[7];
        float* gs = gsum + c * DIMS + 4 * ht;
        float* gq = gsq  + c * DIMS + 4 * ht;
        atomAddF(gs + 0, s.x); atomAddF(gs + 1, s.y);
        atomAddF(gs + 2, s.z); atomAddF(gs + 3, s.w);
        atomAddF(gq + 0, q.x); atomAddF(gq + 1, q.y);
        atomAddF(gq + 2, q.z); atomAddF(gq + 3, q.w);
    }
}

// ---------------- K5: finalize means / withins ----------------
__global__ __launch_bounds__(256) void k_final(const float* __restrict__ gsum,
                                               const float* __restrict__ gsq,
                                               const int* __restrict__ counts,
                                               float* __restrict__ means,
                                               float* __restrict__ withins) {
    const int idx = blockIdx.x * 256 + threadIdx.x;
    if (idx >= NUM_C * DIMS) return;
    const int c = idx >> 9;
    const float n = (float)counts[c];
    const float s = gsum[idx];
    const float m = s / n;
    means[idx] = m;
    const float w = gsq[idx] - s * m;    // == seg((h-m)^2)
    withins[idx] = w > 0.f ? w : 0.f;
}

// ---------------- K6: pairs — x, sort, Simpson betainc on top-d -------------
// I_x(1/2,b) = (2/B(1/2,b)) * Int_0^sqrt(x) (1-s^2)^(b-1) ds  (u = s^2)
// Composite Simpson (256 intervals), f32, split over 8 lanes per x-value.
// B(1/2,b) = sqrt(pi/b) * (1 + 1/(8b) + 1/(128 b^2))  (b ~ 4095 here).
__global__ __launch_bounds__(512) void k_pairs(const float* __restrict__ means,
                                               const float* __restrict__ withins,
                                               const int* __restrict__ counts,
                                               const int* __restrict__ dptr,
                                               float* __restrict__ out) {
    __shared__ float xs[DIMS];
    __shared__ float wsum[8];
    const int tid = threadIdx.x;

    int p = blockIdx.x, i = 0, rem = p;
    while (rem >= NUM_C - 1 - i) { rem -= NUM_C - 1 - i; ++i; }
    const int j = i + 1 + rem;

    const float pc = (float)(counts[i] + counts[j]);

    {
        const float mi = means[i * DIMS + tid], mj = means[j * DIMS + tid];
        const float hd = (mi - mj) * 0.5f;
        const float between = hd * hd * pc;
        const float within = withins[i * DIMS + tid] + withins[j * DIMS + tid];
        float x = between / (between + within);
        if (!(x >= 1e-37f)) x = 1e-37f;          // also catches NaN
        const float XM = 1.0f - 1e-5f;
        if (x > XM) x = XM;
        xs[tid] = x;
    }

    // bitonic sort descending (f32)
    for (int kk = 2; kk <= DIMS; kk <<= 1) {
        for (int jj = kk >> 1; jj > 0; jj >>= 1) {
            __syncthreads();
            const int ixj = tid ^ jj;
            if (ixj > tid) {
                const float va = xs[tid], vb = xs[ixj];
                const bool sw = ((tid & kk) == 0) ? (va < vb) : (va > vb);
                if (sw) { xs[tid] = vb; xs[ixj] = va; }
            }
        }
    }
    __syncthreads();

    const int d = *dptr;
    float d2 = pc - 2.0f;
    if (d2 == 0.0f) d2 = 1e-5f;
    const float b = d2 * 0.5f;
    const float bm1 = b - 1.0f;
    const float invb = 1.0f / b;
    // ln(2/B) = ln2 - [0.5*(ln pi - ln b) + log1p(1/(8b) + 1/(128 b^2))]
    const float ln2overB = 0.69314718f
        - (0.5f * (1.14472989f - logf(b)) + log1pf(invb * (0.125f + 0.0078125f * invb)));

    const int sub = tid & 7;
    const int rounds = (d + 63) >> 6;            // q-groups of 64 per pass
    float part = 0.f;
    for (int r = 0; r < rounds; ++r) {
        const int q = (tid >> 3) + (r << 6);
        const bool act = (q < d);
        const float x = xs[act ? q : 0];
        const float rt = sqrtf(x);
        const float h = rt * (1.0f / 256.0f);
        float acc = 0.f;
        for (int k = sub; k <= 256; k += 8) {
            const float sv = (float)k * h;
            const float w = (k == 0 || k == 256) ? 1.f : ((k & 1) ? 4.f : 2.f);
            acc += w * __expf(bm1 * log1pf(-sv * sv));
        }
        acc += __shfl_down(acc, 4, 64);
        acc += __shfl_down(acc, 2, 64);
        acc += __shfl_down(acc, 1, 64);
        if (sub == 0 && act) {
            float li = logf(acc * h * (1.0f / 3.0f)) + ln2overB;
            part += (li < 0.f) ? li : 0.f;       // betainc <= 1
        }
    }
    for (int off = 32; off > 0; off >>= 1) part += __shfl_down(part, off, 64);
    if ((tid & 63) == 0) wsum[tid >> 6] = part;
    __syncthreads();
    if (tid == 0) {
        float t = 0.f;
        for (int w = 0; w < 8; ++w) t += wsum[w];
        atomAddF(out, -t);
    }
}

// ---------------- launch ----------------
extern "C" void kernel_launch(void* const* d_in, const int* in_sizes, int n_in,
                              void* d_out, int out_size, void* d_ws, size_t ws_size,
                              hipStream_t stream) {
    const float* hidden = (const float*)d_in[0];
    const int* bids = (const int*)d_in[1];
    const int* dptr = (const int*)d_in[2];
    float* out = (float*)d_out;
    const int N = in_sizes[1];

    // ws layout (~394 KB)
    char* ws = (char*)d_ws;
    int* counts   = (int*)(ws + 0);          // 16 ints
    int* offs     = (int*)(ws + 256);        // 16 ints
    int* gcur     = (int*)(ws + 512);        // 16 ints
    float* gsum   = (float*)(ws + 1024);     // 16*512 f32
    float* gsq    = (float*)(ws + 33792);    // 16*512 f32
    float* means  = (float*)(ws + 66560);    // 16*512 f32
    float* withins= (float*)(ws + 99328);    // 16*512 f32
    int* perm     = (int*)(ws + 132096);     // N ints

    hipMemsetAsync(d_ws, 0, 66560, stream);  // counts/offs/gcur/gsum/gsq
    hipMemsetAsync(d_out, 0, sizeof(float), stream);

    const int nb = (N + 1023) / 1024;        // 4 elems/thread, 256 threads
    k_counts <<<nb, 256, 0, stream>>>(bids, counts, N);
    k_prefix <<<1, 64, 0, stream>>>(counts, offs, gcur);
    k_scatter<<<nb, 256, 0, stream>>>(bids, gcur, perm, N);
    k_segsum <<<NUM_C * CHUNKS, 256, 0, stream>>>(hidden, perm, counts, offs, gsum, gsq);
    k_final  <<<(NUM_C * DIMS + 255) / 256, 256, 0, stream>>>(gsum, gsq, counts, means, withins);
    k_pairs  <<<NUM_C * (NUM_C - 1) / 2, 512, 0, stream>>>(means, withins, counts, dptr, out);
}